// Round 12
// baseline (163.537 us; speedup 1.0000x reference)
//
#include <hip/hip_runtime.h>

// OmniShift collapsed to one effective 5x5 depthwise conv per channel.
// x: (8, 192, 256, 256) fp32. 805 MB min traffic.
//
// R12 = R6 rolling ring + R11 global_load_lds DMA + counted vmcnt (T4).
//  - One block per half-plane: 3072 blocks; LDS 33.8KB -> 4 blocks/CU.
//  - 32-slot ring (slot(rr)=(rr+2)&31), 16 phases x 8 rows.
//  - Per phase: [vmcnt(4) lgkm(0); s_barrier] -> issue 2 DMAs (rows 2 phases
//    ahead; no dest VGPRs) -> compute 2 rows/thread from 6 ring rows (dual
//    accumulate, ~40 live VGPR) -> 2 f32x4 stores. vmcnt NEVER drained to 0:
//    K=4 retires exactly the 2-phase-old DMAs, keeps newest DMAs+stores in
//    flight across barriers.
//  - Halo overfetch 12.5% -> 3.1% (only the half-plane seam).
// Lessons kept: no min-waves launch_bounds (R5/R9/R10 spills); no nt stores
// (R3); readfirstlane via bit_cast (R8).

typedef float f32x2 __attribute__((ext_vector_type(2)));
typedef float f32x4 __attribute__((ext_vector_type(4)));

constexpr int Bn = 8, Cn = 192, Hn = 256, Wn = 256;
constexpr int BAND    = 128;         // rows per block
constexpr int PH      = 8;           // rows per phase
constexpr int NPH     = BAND / PH;   // 16
constexpr int SLOTS   = 32;          // ring rows; slot(rr) = (rr+2) & 31
constexpr int LSTRIDE = 264;         // 4 + 256 + 4 f32; col w at pos w+4
constexpr int NBLK    = Bn * Cn * (Hn / BAND);   // 3072

__device__ __forceinline__ float uniformf(float v) {
    return __builtin_bit_cast(float,
        __builtin_amdgcn_readfirstlane(__builtin_bit_cast(int, v)));
}

__device__ __forceinline__ void gload16(const float* g, float* l) {
    __builtin_amdgcn_global_load_lds(
        (const __attribute__((address_space(1))) unsigned int*)g,
        (__attribute__((address_space(3))) unsigned int*)l, 16, 0, 0);
}

__global__ __launch_bounds__(256)
void omnishift_kernel(const float* __restrict__ x,
                      const float* __restrict__ w1,
                      const float* __restrict__ w3,
                      const float* __restrict__ w5,
                      const float* __restrict__ alpha,
                      float* __restrict__ out)
{
    __shared__ float lds[SLOTS * LSTRIDE];   // 33792 B -> 4 blocks/CU

    const int tid   = threadIdx.x;
    const int ct    = tid & 63;    // column group: cols 4ct..4ct+3
    const int rg    = tid >> 6;    // wave id 0..3
    const int band  = blockIdx.x & 1;
    const int plane = blockIdx.x >> 1;   // b*C + c
    const int r0    = band * BAND;
    const int c     = plane % Cn;

    // ---- effective 5x5 weights -> SGPRs ----
    const float a0 = alpha[0], a1 = alpha[1], a2 = alpha[2], a3 = alpha[3];
    float wfs[5][5];
#pragma unroll
    for (int i = 0; i < 5; ++i)
#pragma unroll
        for (int j = 0; j < 5; ++j) {
            float v = a3 * w5[(c * 5 + i) * 5 + j];
            if (i >= 1 && i <= 3 && j >= 1 && j <= 3)
                v += a2 * w3[(c * 3 + (i - 1)) * 3 + (j - 1)];
            if (i == 2 && j == 2)
                v += a1 * w1[c] + a0;
            wfs[i][j] = uniformf(v);
        }

    const float* xp = x   + (size_t)plane * (Hn * Wn);
    float*       op = out + (size_t)plane * (Hn * Wn);

    // ---- zero side-halo cols (pos 2,3 = cols -2,-1; 260,261 = 256,257) ----
    if (tid < SLOTS * 4) {
        const int r   = tid >> 2;
        const int q   = tid & 3;
        const int pos = (q < 2) ? (2 + q) : (258 + q);
        lds[r * LSTRIDE + pos] = 0.f;
    }

    // ---- prologue: ring rows rr=-2..17 -> slots 0..19 (5 DMAs/thread) ----
    // per-wave issue order: i=0,1,2 ("part1", slots 0..11) then i=3,4 ("part2")
#pragma unroll
    for (int i = 0; i < 5; ++i) {
        const int idx = tid + i * 256;       // 20 rows * 64 lanes
        const int row = idx >> 6;            // wave-uniform; slot = row
        const int l   = idx & 63;
        const int gr  = r0 + row - 2;
        float* dst = &lds[row * LSTRIDE + 4];    // uniform base; HW adds lane*16
        if (gr >= 0) {                           // gr<=255 always in prologue
            gload16(xp + (size_t)gr * Wn + 4 * l, dst);
        } else {                                 // band 0, rows -2,-1
            f32x2 z = {0.f, 0.f};
            f32x2* d2 = reinterpret_cast<f32x2*>(dst + 4 * l);
            d2[0] = z; d2[1] = z;
        }
    }

#pragma unroll 1
    for (int p = 0; p < NPH; ++p) {
        // -- 0) wait 2-phase-old DMAs (counted, never 0) + barrier --
        // K=4 allows [prev DMA(<=2) + prev stores(2)]; phase 0: only part2(2).
        if (p == 0)
            asm volatile("s_waitcnt vmcnt(2) lgkmcnt(0)\n\ts_barrier" ::: "memory");
        else
            asm volatile("s_waitcnt vmcnt(4) lgkmcnt(0)\n\ts_barrier" ::: "memory");

        // -- 1) issue prefetch DMAs: ring rows rr = 8p+18+2rg, +1 --
#pragma unroll
        for (int k = 0; k < 2; ++k) {
            const int rr = 8 * p + 18 + 2 * rg + k;
            if (rr <= BAND + 1) {                // needed window ends at 129
                const int gr   = r0 + rr;
                const int slot = (rr + 2) & (SLOTS - 1);
                float* dst = &lds[slot * LSTRIDE + 4];
                if (gr <= Hn - 1) {
                    gload16(xp + (size_t)gr * Wn + 4 * ct, dst);
                } else {                          // band 1, rows 256,257 -> zeros
                    f32x2 z = {0.f, 0.f};
                    f32x2* d2 = reinterpret_cast<f32x2*>(dst + 4 * ct);
                    d2[0] = z; d2[1] = z;
                }
            }
        }

        // -- 2) compute output rows A = 8p+2rg, A+1 from 6 ring rows --
        const int s0 = (8 * p + 2 * rg) & (SLOTS - 1);   // slot of row A-2
        f32x4 accA = {0.f,0.f,0.f,0.f}, accB = {0.f,0.f,0.f,0.f};
#pragma unroll
        for (int off = 0; off < 6; ++off) {
            int sl = s0 + off; if (sl >= SLOTS) sl -= SLOTS;
            // 8 floats: cols 4ct-2..4ct+5 = pos 4ct+2..4ct+9 (8B-aligned)
            const f32x2* src = reinterpret_cast<const f32x2*>(
                &lds[sl * LSTRIDE + 4 * ct + 2]);
            float rw[8];
#pragma unroll
            for (int h = 0; h < 4; ++h) {
                f32x2 pr = src[h];
                rw[2 * h] = pr.x; rw[2 * h + 1] = pr.y;
            }
            if (off <= 4) {
#pragma unroll
                for (int d = 0; d < 5; ++d)
#pragma unroll
                    for (int j = 0; j < 4; ++j)
                        accA[j] += rw[j + d] * wfs[off][d];
            }
            if (off >= 1) {
#pragma unroll
                for (int d = 0; d < 5; ++d)
#pragma unroll
                    for (int j = 0; j < 4; ++j)
                        accB[j] += rw[j + d] * wfs[off - 1][d];
            }
        }

        // -- 3) output stores (stay in flight across barriers) --
        float* outp = op + (size_t)(r0 + 8 * p + 2 * rg) * Wn + 4 * ct;
        *reinterpret_cast<f32x4*>(outp)      = accA;
        *reinterpret_cast<f32x4*>(outp + Wn) = accB;
    }
}

extern "C" void kernel_launch(void* const* d_in, const int* in_sizes, int n_in,
                              void* d_out, int out_size, void* d_ws, size_t ws_size,
                              hipStream_t stream)
{
    const float* x     = (const float*)d_in[0];
    const float* w1    = (const float*)d_in[1];
    const float* w3    = (const float*)d_in[2];
    const float* w5    = (const float*)d_in[3];
    const float* alpha = (const float*)d_in[4];
    float* out = (float*)d_out;

    omnishift_kernel<<<NBLK, 256, 0, stream>>>(x, w1, w3, w5, alpha, out);
}

// Round 13
// 149.858 us; speedup vs baseline: 1.0913x; 1.0913x over previous
//
#include <hip/hip_runtime.h>

// OmniShift collapsed to one effective 5x5 depthwise conv per channel.
// x: (8, 192, 256, 256) fp32. 805 MB min traffic.
//
// R13 = R11 (best: 151.0us) + XCD-chunked blockIdx swizzle, nothing else.
//  R11 proved DMA staging (global_load_lds w=16) breaks the 157us plateau.
//  R12 proved fine-grained ring phasing REGRESSES (163.5) -> keep coarse
//  stage-all -> sync -> compute-all shape.
//  This round: adjacent bands (sharing 4 halo rows = 50MB chip-wide refetch)
//  land on the same XCD's L2 -> seam fetch becomes L2 hit. Single change vs
//  R11 to isolate the byte/L2 lever in the DMA regime (R4's neutral swizzle
//  predates DMA staging - different bottleneck regime).
// Lessons kept: no min-waves launch_bounds (R5/R9/R10 spills), no nt stores
// (R3), readfirstlane via bit_cast (R8), no per-phase barriers (R12).

typedef float f32x2 __attribute__((ext_vector_type(2)));
typedef float f32x4 __attribute__((ext_vector_type(4)));

constexpr int Bn = 8, Cn = 192, Hn = 256, Wn = 256;
constexpr int TR      = 32;          // output rows per block
constexpr int LROWS   = TR + 4;      // 36 staged rows
constexpr int LSTRIDE = 264;         // 4 + 256 + 4 f32; data col w at pos w+4
constexpr int BANDS   = Hn / TR;     // 8
constexpr int NWG     = Bn * Cn * BANDS;   // 12288; %8==0 -> swizzle bijective
constexpr int CHUNK   = NWG / 8;           // 1536 blocks per XCD

__device__ __forceinline__ float uniformf(float v) {
    return __builtin_bit_cast(float,
        __builtin_amdgcn_readfirstlane(__builtin_bit_cast(int, v)));
}

__device__ __forceinline__ void gload16(const float* g, float* l) {
    __builtin_amdgcn_global_load_lds(
        (const __attribute__((address_space(1))) unsigned int*)g,
        (__attribute__((address_space(3))) unsigned int*)l, 16, 0, 0);
}

__global__ __launch_bounds__(256)
void omnishift_kernel(const float* __restrict__ x,
                      const float* __restrict__ w1,
                      const float* __restrict__ w3,
                      const float* __restrict__ w5,
                      const float* __restrict__ alpha,
                      float* __restrict__ out)
{
    __shared__ float lds[LROWS * LSTRIDE];   // 38016 B -> 4 blocks/CU

    const int tid   = threadIdx.x;
    // XCD swizzle: dispatcher round-robins blockIdx across 8 XCDs; remap so
    // each XCD gets a contiguous chunk -> band-adjacent blocks share its L2.
    const int wg    = (blockIdx.x & 7) * CHUNK + (blockIdx.x >> 3);
    const int band  = wg % BANDS;
    const int plane = wg / BANDS;            // b*C + c
    const int c     = plane % Cn;
    const int r0    = band * TR;

    // ---- effective 5x5 weights (block-uniform -> SGPRs) ----
    const float a0 = alpha[0], a1 = alpha[1], a2 = alpha[2], a3 = alpha[3];
    float wf[5][5];
#pragma unroll
    for (int i = 0; i < 5; ++i)
#pragma unroll
        for (int j = 0; j < 5; ++j) {
            float v = a3 * w5[(c * 5 + i) * 5 + j];
            if (i >= 1 && i <= 3 && j >= 1 && j <= 3)
                v += a2 * w3[(c * 3 + (i - 1)) * 3 + (j - 1)];
            if (i == 2 && j == 2)
                v += a1 * w1[c] + a0;
            wf[i][j] = uniformf(v);
        }

    const float* xp = x + (size_t)plane * (Hn * Wn);

    // ---- zero halo cols: pos 2,3 (cols -2,-1), 260,261 (cols 256,257) ----
    if (tid < LROWS * 4) {
        const int r   = tid >> 2;
        const int q   = tid & 3;
        const int pos = (q < 2) ? (2 + q) : (258 + q);
        lds[r * LSTRIDE + pos] = 0.f;
    }

    // ---- stage 36 rows via HBM->LDS DMA (9 issues/thread, no dest regs) ----
#pragma unroll
    for (int i = 0; i < 9; ++i) {
        const int idx = tid + i * 256;       // 0..2303 = 36 rows * 64 lanes
        const int row = idx >> 6;            // wave-uniform
        const int l   = idx & 63;            // lane id
        const int gr  = r0 - 2 + row;
        float* dst = &lds[row * LSTRIDE + 4];         // uniform base; HW adds lane*16
        if ((unsigned)gr < (unsigned)Hn) {
            gload16(xp + (size_t)gr * Wn + 4 * l, dst);
        } else {
            f32x2 z = {0.f, 0.f};
            f32x2* d = reinterpret_cast<f32x2*>(dst + 4 * l);
            d[0] = z; d[1] = z;
        }
    }
    __syncthreads();   // drains DMA (vmcnt) + lgkm -> tile complete

    // ---- compute: thread = 4-col strip x 8 rows, 5x8 sliding window ----
    const int ct     = tid & 63;
    const int rg     = tid >> 6;
    const int oc0    = 4 * ct;
    const int lrbase = rg * 8;

    float* outp = out + (size_t)plane * (Hn * Wn)
                      + (size_t)(r0 + rg * 8) * Wn + oc0;

    // window row = cols oc0-2..oc0+5 = pos oc0+2..oc0+9: 4x ds_read_b64
    auto ldrow = [&](int lr, float w[8]) {
        const f32x2* src = reinterpret_cast<const f32x2*>(
            &lds[lr * LSTRIDE + oc0 + 2]);           // byte 8-aligned
#pragma unroll
        for (int h = 0; h < 4; ++h) {
            f32x2 p = src[h];
            w[2 * h] = p.x; w[2 * h + 1] = p.y;
        }
    };

    float win[5][8];
#pragma unroll
    for (int i = 0; i < 4; ++i) ldrow(lrbase + i, win[i]);

#pragma unroll
    for (int k = 0; k < 8; ++k) {
        ldrow(lrbase + 4 + k, win[4]);

        f32x4 o;
#pragma unroll
        for (int j = 0; j < 4; ++j) {
            float acc = 0.f;
#pragma unroll
            for (int i = 0; i < 5; ++i)
#pragma unroll
                for (int d = 0; d < 5; ++d)
                    acc += win[i][j + d] * wf[i][d];
            o[j] = acc;
        }
        *reinterpret_cast<f32x4*>(outp + (size_t)k * Wn) = o;

#pragma unroll
        for (int i = 0; i < 4; ++i)
#pragma unroll
            for (int j = 0; j < 8; ++j) win[i][j] = win[i + 1][j];
    }
}

extern "C" void kernel_launch(void* const* d_in, const int* in_sizes, int n_in,
                              void* d_out, int out_size, void* d_ws, size_t ws_size,
                              hipStream_t stream)
{
    const float* x     = (const float*)d_in[0];
    const float* w1    = (const float*)d_in[1];
    const float* w3    = (const float*)d_in[2];
    const float* w5    = (const float*)d_in[3];
    const float* alpha = (const float*)d_in[4];
    float* out = (float*)d_out;

    omnishift_kernel<<<NWG, 256, 0, stream>>>(x, w1, w3, w5, alpha, out);
}